// Round 8
// baseline (1446.635 us; speedup 1.0000x reference)
//
#include <hip/hip_runtime.h>

#define NUM_USERS 60000
#define NUM_ITEMS 40000
#define NUM_NODES 100000
#define DIM       64
#define NUM_EDGES 1200000
#define BATCH     16384

#define BROWS 64                  // rows per bucket (= LDS tile rows)
#define NBUCK 1563                // ceil(100000/64)
#define CAP   1024                // padded slots per bucket (mean 768, +9.2 sigma)
#define EPB   4096                // edges per bin_edges block -> 293 blocks

// ---------------------------------------------------------------------------
// 1) bin edges into 1563 coarse buckets (padded regions, cursors start at 0),
//    and inline the batch-row flagging for layer-3 sparsification.
//    Packed u64: [val:32][lrow:6][col:17]
// ---------------------------------------------------------------------------
__global__ __launch_bounds__(256) void bin_edges(
    const int* __restrict__ rows, const int* __restrict__ cols,
    const float* __restrict__ vals,
    const int* __restrict__ uidx, const int* __restrict__ iidx,
    int* __restrict__ gcursor, unsigned* __restrict__ flags,
    unsigned long long* __restrict__ tmp)
{
    __shared__ int cnt[NBUCK], lcur[NBUCK], gbase[NBUCK];
    int t = threadIdx.x;
    for (int i = t; i < NBUCK; i += 256) { cnt[i] = 0; lcur[i] = 0; }
    // inline flag_batch: this block's slice of the 2*BATCH indices
    int fbase = blockIdx.x * 112;
    for (int k = t; k < 112; k += 256) {
        int gi = fbase + k;
        if (gi < BATCH) {
            int n = uidx[gi];
            atomicOr(&flags[n >> 5], 1u << (n & 31));
        } else if (gi < 2 * BATCH) {
            int n = NUM_USERS + iidx[gi - BATCH];
            atomicOr(&flags[n >> 5], 1u << (n & 31));
        }
    }
    __syncthreads();
    int base = blockIdx.x * EPB;
    int lim = NUM_EDGES - base; if (lim > EPB) lim = EPB;
    // pass 1: count
    for (int k = t; k < lim; k += 256)
        atomicAdd(&cnt[rows[base + k] >> 6], 1);
    __syncthreads();
    // reserve per-bucket runs (cursors relative to bucket base)
    for (int i = t; i < NBUCK; i += 256) {
        int c = cnt[i];
        gbase[i] = c ? atomicAdd(&gcursor[i], c) : 0;
    }
    __syncthreads();
    // pass 2: write
    for (int k = t; k < lim; k += 256) {
        int idx = base + k;
        int r = rows[idx];
        int b = r >> 6;
        int lofs = atomicAdd(&lcur[b], 1);
        unsigned long long packed =
            ((unsigned long long)(unsigned)__float_as_int(vals[idx]) << 32)
            | ((unsigned)(r & 63) << 17) | (unsigned)cols[idx];
        tmp[((size_t)b << 10) + gbase[b] + lofs] = packed;
    }
}

// ---------------------------------------------------------------------------
// 2) bucket SpMM: one block per 64-row bucket. Edges consumed in arbitrary
//    order from the padded bucket; LDS fp32 atomic accumulation into a
//    64x64 tile; coalesced float4 write-out. Metadata broadcast via
//    v_readlane (uniform scalars) -> branch-free inner loop, SGPR-base
//    gathers, compiler-hoistable load pipeline.
//    FILTER: skip rows not in the flag mask (layer 3) by zeroing col/val.
// ---------------------------------------------------------------------------
template<bool FILTER>
__global__ __launch_bounds__(256) void spmm_bucket(
    const unsigned long long* __restrict__ tmp, const int* __restrict__ gcursor,
    const float* __restrict__ xu, const float* __restrict__ xi,
    float* __restrict__ y, const unsigned* __restrict__ flags)
{
    __shared__ float tile[BROWS][DIM];   // 16 KB
    int b = blockIdx.x;
    int t = threadIdx.x;
    int count = gcursor[b];
    const unsigned long long* src = tmp + ((size_t)b << 10);
    for (int i = t; i < BROWS * DIM; i += 256) ((float*)tile)[i] = 0.f;
    unsigned long long fmask = ~0ull;
    if (FILTER) fmask = ((unsigned long long)flags[2 * b + 1] << 32) | flags[2 * b];
    __syncthreads();

    int wave = t >> 6, lane = t & 63;
    for (int cb = wave * 64; cb < count; cb += 256) {
        int idx = cb + lane;
        // invalid lanes -> m=0 -> col=0,val=0: cached row-0 gather adding 0.0
        unsigned long long m = (idx < count) ? src[idx] : 0ull;
        int colv = (int)(m & 0x1FFFF);
        int lrv  = (int)((m >> 17) & 63);
        int valv = (int)(m >> 32);
        #pragma unroll
        for (int j = 0; j < 64; ++j) {
            int cj = __builtin_amdgcn_readlane(colv, j);
            int lr = __builtin_amdgcn_readlane(lrv, j);
            int vb = __builtin_amdgcn_readlane(valv, j);
            if (FILTER) {
                int keep = (int)((fmask >> lr) & 1);
                cj = keep ? cj : 0;     // skipped edges gather hot row 0
                vb = keep ? vb : 0;     // and add exact 0.0
            }
            const float* s = (cj < NUM_USERS)
                ? xu + ((size_t)cj << 6)
                : xi + ((size_t)(cj - NUM_USERS) << 6);
            float xval = s[lane];
            atomicAdd(&tile[lr][lane], __int_as_float(vb) * xval);
        }
    }
    __syncthreads();

    // coalesced write-out (FILTER: only flagged rows)
    float4* y4 = (float4*)y;
    for (int i = t; i < BROWS * (DIM / 4); i += 256) {
        int lr = i >> 4, q = i & 15;
        int row = b * BROWS + lr;
        if (row < NUM_NODES && (!FILTER || ((fmask >> lr) & 1)))
            y4[((size_t)row << 4) + q] = ((const float4*)tile[lr])[q];
    }
}

// ---------------------------------------------------------------------------
// 3) batched dot: one wave per batch element
// ---------------------------------------------------------------------------
__global__ __launch_bounds__(256) void dot_kernel(
    const int*   __restrict__ uidx,
    const int*   __restrict__ iidx,
    const float* __restrict__ x,
    float*       __restrict__ out)
{
    int wid  = (blockIdx.x * blockDim.x + threadIdx.x) >> 6;
    int lane = threadIdx.x & 63;
    if (wid >= BATCH) return;
    int u  = uidx[wid];
    int it = iidx[wid];
    float a = x[(size_t)u * DIM + lane];
    float bb = x[((size_t)NUM_USERS + it) * DIM + lane];
    float p = a * bb;
    #pragma unroll
    for (int off = 32; off > 0; off >>= 1)
        p += __shfl_down(p, off);
    if (lane == 0) out[wid] = p;
}

extern "C" void kernel_launch(void* const* d_in, const int* in_sizes, int n_in,
                              void* d_out, int out_size, void* d_ws, size_t ws_size,
                              hipStream_t stream)
{
    const int*   user_indices = (const int*)  d_in[0];
    const int*   item_indices = (const int*)  d_in[1];
    const int*   edge_rows    = (const int*)  d_in[2];
    const int*   edge_cols    = (const int*)  d_in[3];
    const float* edge_vals    = (const float*)d_in[4];
    const float* user_emb     = (const float*)d_in[5];
    const float* item_emb     = (const float*)d_in[6];
    float*       out          = (float*)      d_out;

    // ---- workspace layout ----
    const size_t nfloats = (size_t)NUM_NODES * DIM;   // 6.4M floats
    char* p = (char*)d_ws;
    unsigned long long* tmp = (unsigned long long*)p;
    p += (size_t)NBUCK * CAP * 8;                     // 12.8 MB, persists all layers
    float*    bufA    = (float*)p;    p += nfloats * 4;   // 25.6 MB
    float*    bufB    = (float*)p;    p += nfloats * 4;   // 25.6 MB
    int*      gcursor = (int*)p;      p += 2048 * 4;      // contiguous with flags
    unsigned* flags   = (unsigned*)p; p += 3200 * 4;      // 100K bits

    const int NB_BIN = (NUM_EDGES + EPB - 1) / EPB;   // 293

    // ---- clear cursors + flags (one memset), then bin + flag in one kernel ----
    hipMemsetAsync(gcursor, 0, (2048 + 3200) * sizeof(int), stream);
    bin_edges<<<NB_BIN, 256, 0, stream>>>(
        edge_rows, edge_cols, edge_vals, user_indices, item_indices,
        gcursor, flags, tmp);

    // ---- 3 SpMM layers straight from buckets (no CSR, no sort) ----
    spmm_bucket<false><<<NBUCK, 256, 0, stream>>>(
        tmp, gcursor, user_emb, item_emb, bufA, nullptr);
    spmm_bucket<false><<<NBUCK, 256, 0, stream>>>(
        tmp, gcursor, bufA, bufA + (size_t)NUM_USERS * DIM, bufB, nullptr);
    spmm_bucket<true><<<NBUCK, 256, 0, stream>>>(
        tmp, gcursor, bufB, bufB + (size_t)NUM_USERS * DIM, bufA, flags);

    // ---- final dot ----
    dot_kernel<<<(BATCH * 64) / 256, 256, 0, stream>>>(
        user_indices, item_indices, bufA, out);
}

// Round 9
// 1231.486 us; speedup vs baseline: 1.1747x; 1.1747x over previous
//
#include <hip/hip_runtime.h>

#define NUM_USERS 60000
#define NUM_ITEMS 40000
#define NUM_NODES 100000
#define DIM       64
#define NUM_EDGES 1200000
#define BATCH     16384

#define BROWS 128                 // rows per bucket
#define NBUCK 782                 // ceil(100000/128)
#define CAP   2048                // padded slots per bucket (mean 1536, +13 sigma)
#define EPB   4096                // edges per bin_edges block -> 293 blocks
#define NCT   13                  // col tiles of 8192 cols (2 MB of x each)
#define NFLAGW 3125               // 100000 bits in u32 words

// ---------------------------------------------------------------------------
// 1) bin edges into 782 row-buckets (padded regions) + fused batch-row flagging
//    Packed u64: [val:32][lrow:7][col:17]
// ---------------------------------------------------------------------------
__global__ __launch_bounds__(256) void bin_edges(
    const int* __restrict__ rows, const int* __restrict__ cols,
    const float* __restrict__ vals,
    const int* __restrict__ uidx, const int* __restrict__ iidx,
    int* __restrict__ gcursor, unsigned* __restrict__ flags,
    unsigned long long* __restrict__ tmp)
{
    __shared__ int cnt[NBUCK], lcur[NBUCK], gbase[NBUCK];
    int t = threadIdx.x;
    for (int i = t; i < NBUCK; i += 256) { cnt[i] = 0; lcur[i] = 0; }
    // fused flag_batch: this block's slice of the 2*BATCH indices
    int fbase = blockIdx.x * 112;
    for (int k = t; k < 112; k += 256) {
        int gi = fbase + k;
        if (gi < BATCH) {
            int n = uidx[gi];
            atomicOr(&flags[n >> 5], 1u << (n & 31));
        } else if (gi < 2 * BATCH) {
            int n = NUM_USERS + iidx[gi - BATCH];
            atomicOr(&flags[n >> 5], 1u << (n & 31));
        }
    }
    __syncthreads();
    int base = blockIdx.x * EPB;
    int lim = NUM_EDGES - base; if (lim > EPB) lim = EPB;
    for (int k = t; k < lim; k += 256)
        atomicAdd(&cnt[rows[base + k] >> 7], 1);
    __syncthreads();
    for (int i = t; i < NBUCK; i += 256) {
        int c = cnt[i];
        gbase[i] = c ? atomicAdd(&gcursor[i], c) : 0;
    }
    __syncthreads();
    for (int k = t; k < lim; k += 256) {
        int idx = base + k;
        int r = rows[idx];
        int b = r >> 7;
        int lofs = atomicAdd(&lcur[b], 1);
        unsigned long long packed =
            ((unsigned long long)(unsigned)__float_as_int(vals[idx]) << 32)
            | ((unsigned)(r & 127) << 17) | (unsigned)cols[idx];
        tmp[(size_t)b * CAP + gbase[b] + lofs] = packed;
    }
}

// ---------------------------------------------------------------------------
// 2) per-bucket counting sort by col-tile (col>>13): creates the moving
//    gather window. In/out via LDS stages, coalesced global read+write.
// ---------------------------------------------------------------------------
__global__ __launch_bounds__(256) void sort_ct(
    const int* __restrict__ gcursor, unsigned long long* __restrict__ tmp)
{
    __shared__ unsigned long long stage[CAP], stage2[CAP];
    __shared__ int tcnt[NCT + 1], tcur[NCT];
    int b = blockIdx.x, t = threadIdx.x;
    int count = gcursor[b];
    unsigned long long* src = tmp + (size_t)b * CAP;
    if (t < NCT + 1) tcnt[t] = 0;
    __syncthreads();
    for (int i = t; i < count; i += 256) {
        unsigned long long v = src[i];
        stage[i] = v;
        atomicAdd(&tcnt[(int)((v & 0x1FFFF) >> 13)], 1);
    }
    __syncthreads();
    if (t == 0) {
        int run = 0;
        for (int c = 0; c < NCT; ++c) { int x = tcnt[c]; tcur[c] = run; run += x; }
    }
    __syncthreads();
    for (int i = t; i < count; i += 256) {
        unsigned long long v = stage[i];
        int pos = atomicAdd(&tcur[(int)((v & 0x1FFFF) >> 13)], 1);
        stage2[pos] = v;
    }
    __syncthreads();
    for (int i = t; i < count; i += 256)
        src[i] = stage2[i];
}

// ---------------------------------------------------------------------------
// 3) SpMM from col-sorted buckets: one block per 128-row bucket, 16-lane
//    groups each own an edge (float4/lane gather, 2x unroll -> 32 gathers in
//    flight/block), LDS ds_add_f32 accumulate into padded 128x68 tile,
//    coalesced float4 writeout. FILTER: layer-3 needed-rows only.
// ---------------------------------------------------------------------------
template<bool FIRST>
__device__ __forceinline__ const float4* xbase(
    int c, const float4* __restrict__ xu, const float4* __restrict__ xi)
{
    if (FIRST)
        return (c < NUM_USERS) ? xu + ((size_t)c << 4)
                               : xi + ((size_t)(c - NUM_USERS) << 4);
    return xu + ((size_t)c << 4);
}

template<bool FIRST, bool FILTER>
__global__ __launch_bounds__(256) void spmm_tile(
    const unsigned long long* __restrict__ tmp, const int* __restrict__ gcursor,
    const float* __restrict__ xu_, const float* __restrict__ xi_,
    float* __restrict__ y, const unsigned* __restrict__ flags)
{
    __shared__ float tile[BROWS][68];   // pad 68: 16B-aligned rows, bank-shifted
    int b = blockIdx.x, t = threadIdx.x;
    int count = gcursor[b];
    const unsigned long long* src = tmp + (size_t)b * CAP;
    const float4* xu = (const float4*)xu_;
    const float4* xi = (const float4*)xi_;
    for (int i = t; i < BROWS * 68; i += 256) ((float*)tile)[i] = 0.f;
    unsigned long long f0 = ~0ull, f1 = ~0ull;
    if (FILTER) {
        f0 = ((unsigned long long)flags[b * 4 + 1] << 32) | flags[b * 4 + 0];
        f1 = ((unsigned long long)flags[b * 4 + 3] << 32) | flags[b * 4 + 2];
    }
    __syncthreads();

    int gid = t >> 4, q = t & 15;
    int e = gid;
    if (!FILTER) {
        for (; e + 16 < count; e += 32) {
            unsigned long long m0 = src[e];
            unsigned long long m1 = src[e + 16];
            int c0 = (int)(m0 & 0x1FFFF), c1 = (int)(m1 & 0x1FFFF);
            int r0 = (int)((m0 >> 17) & 127), r1 = (int)((m1 >> 17) & 127);
            float v0 = __int_as_float((int)(m0 >> 32));
            float v1 = __int_as_float((int)(m1 >> 32));
            float4 x0 = xbase<FIRST>(c0, xu, xi)[q];
            float4 x1 = xbase<FIRST>(c1, xu, xi)[q];
            float* t0 = &tile[r0][4 * q];
            float* t1 = &tile[r1][4 * q];
            atomicAdd(t0 + 0, v0 * x0.x); atomicAdd(t0 + 1, v0 * x0.y);
            atomicAdd(t0 + 2, v0 * x0.z); atomicAdd(t0 + 3, v0 * x0.w);
            atomicAdd(t1 + 0, v1 * x1.x); atomicAdd(t1 + 1, v1 * x1.y);
            atomicAdd(t1 + 2, v1 * x1.z); atomicAdd(t1 + 3, v1 * x1.w);
        }
    }
    for (; e < count; e += 16) {
        unsigned long long m0 = src[e];
        int c0 = (int)(m0 & 0x1FFFF);
        int r0 = (int)((m0 >> 17) & 127);
        float v0 = __int_as_float((int)(m0 >> 32));
        if (FILTER) {
            unsigned long long w = (r0 < 64) ? f0 : f1;
            if (!((w >> (r0 & 63)) & 1)) continue;
        }
        float4 x0 = xbase<FIRST>(c0, xu, xi)[q];
        float* t0 = &tile[r0][4 * q];
        atomicAdd(t0 + 0, v0 * x0.x); atomicAdd(t0 + 1, v0 * x0.y);
        atomicAdd(t0 + 2, v0 * x0.z); atomicAdd(t0 + 3, v0 * x0.w);
    }
    __syncthreads();

    float4* y4 = (float4*)y;
    for (int i = t; i < BROWS * 16; i += 256) {
        int lr = i >> 4, qq = i & 15;
        int row = b * BROWS + lr;
        bool keep = true;
        if (FILTER) {
            unsigned long long w = (lr < 64) ? f0 : f1;
            keep = ((w >> (lr & 63)) & 1) != 0;
        }
        if (row < NUM_NODES && keep) {
            float4 v = make_float4(tile[lr][4 * qq + 0], tile[lr][4 * qq + 1],
                                   tile[lr][4 * qq + 2], tile[lr][4 * qq + 3]);
            y4[((size_t)row << 4) + qq] = v;
        }
    }
}

// ---------------------------------------------------------------------------
// 4) batched dot: one wave per batch element
// ---------------------------------------------------------------------------
__global__ __launch_bounds__(256) void dot_kernel(
    const int*   __restrict__ uidx,
    const int*   __restrict__ iidx,
    const float* __restrict__ x,
    float*       __restrict__ out)
{
    int wid  = (blockIdx.x * blockDim.x + threadIdx.x) >> 6;
    int lane = threadIdx.x & 63;
    if (wid >= BATCH) return;
    int u  = uidx[wid];
    int it = iidx[wid];
    float a = x[(size_t)u * DIM + lane];
    float bb = x[((size_t)NUM_USERS + it) * DIM + lane];
    float p = a * bb;
    #pragma unroll
    for (int off = 32; off > 0; off >>= 1)
        p += __shfl_down(p, off);
    if (lane == 0) out[wid] = p;
}

extern "C" void kernel_launch(void* const* d_in, const int* in_sizes, int n_in,
                              void* d_out, int out_size, void* d_ws, size_t ws_size,
                              hipStream_t stream)
{
    const int*   user_indices = (const int*)  d_in[0];
    const int*   item_indices = (const int*)  d_in[1];
    const int*   edge_rows    = (const int*)  d_in[2];
    const int*   edge_cols    = (const int*)  d_in[3];
    const float* edge_vals    = (const float*)d_in[4];
    const float* user_emb     = (const float*)d_in[5];
    const float* item_emb     = (const float*)d_in[6];
    float*       out          = (float*)      d_out;

    // ---- workspace layout ----
    const size_t nfloats = (size_t)NUM_NODES * DIM;   // 6.4M floats
    char* p = (char*)d_ws;
    unsigned long long* tmp = (unsigned long long*)p;
    p += (size_t)NBUCK * CAP * 8;                     // 12.8 MB
    float*    bufA    = (float*)p;    p += nfloats * 4;   // 25.6 MB
    float*    bufB    = (float*)p;    p += nfloats * 4;   // 25.6 MB
    int*      gcursor = (int*)p;      p += 1024 * 4;
    unsigned* flags   = (unsigned*)p; p += 3200 * 4;      // 100K bits (+pad)

    const int NB_BIN = (NUM_EDGES + EPB - 1) / EPB;   // 293

    // ---- clear cursors+flags, bin (+flag), col-tile sort ----
    hipMemsetAsync(gcursor, 0, (1024 + 3200) * sizeof(int), stream);
    bin_edges<<<NB_BIN, 256, 0, stream>>>(
        edge_rows, edge_cols, edge_vals, user_indices, item_indices,
        gcursor, flags, tmp);
    sort_ct<<<NBUCK, 256, 0, stream>>>(gcursor, tmp);

    // ---- 3 SpMM layers (layer 1 fuses concat; layer 3 needed rows only) ----
    spmm_tile<true,  false><<<NBUCK, 256, 0, stream>>>(
        tmp, gcursor, user_emb, item_emb, bufA, nullptr);
    spmm_tile<false, false><<<NBUCK, 256, 0, stream>>>(
        tmp, gcursor, bufA, bufA, bufB, nullptr);
    spmm_tile<false, true><<<NBUCK, 256, 0, stream>>>(
        tmp, gcursor, bufB, bufB, bufA, flags);

    // ---- final dot ----
    dot_kernel<<<(BATCH * 64) / 256, 256, 0, stream>>>(
        user_indices, item_indices, bufA, out);
}

// Round 10
// 176.818 us; speedup vs baseline: 8.1815x; 6.9647x over previous
//
#include <hip/hip_runtime.h>

#define NUM_USERS 60000
#define NUM_ITEMS 40000
#define NUM_NODES 100000
#define DIM       64
#define NUM_EDGES 1200000
#define BATCH     16384

#define BROWS 128                 // rows per bucket
#define NBUCK 782                 // ceil(100000/128)
#define CAP   2048                // padded slots per bucket (mean 1536, +13 sigma)
#define EPB   4096                // edges per bin_edges block -> 293 blocks
#define NBINS 2048                // 128 rows x 16 col-tile slots (col>>13: 0..12)
#define NFLAGW 3125               // 100000 bits in u32 words

// ---------------------------------------------------------------------------
// 1) bin edges into 782 row-buckets (padded, cursors start at 0) + fused
//    batch-row flagging. Packed u64: [val:32][lrow:7][col:17]
// ---------------------------------------------------------------------------
__global__ __launch_bounds__(256) void bin_edges(
    const int* __restrict__ rows, const int* __restrict__ cols,
    const float* __restrict__ vals,
    const int* __restrict__ uidx, const int* __restrict__ iidx,
    int* __restrict__ gcursor, unsigned* __restrict__ flags,
    unsigned long long* __restrict__ tmp)
{
    __shared__ int cnt[NBUCK], lcur[NBUCK], gbase[NBUCK];
    int t = threadIdx.x;
    for (int i = t; i < NBUCK; i += 256) { cnt[i] = 0; lcur[i] = 0; }
    // fused flag_batch: this block's slice of the 2*BATCH indices
    int fbase = blockIdx.x * 112;
    for (int k = t; k < 112; k += 256) {
        int gi = fbase + k;
        if (gi < BATCH) {
            int n = uidx[gi];
            atomicOr(&flags[n >> 5], 1u << (n & 31));
        } else if (gi < 2 * BATCH) {
            int n = NUM_USERS + iidx[gi - BATCH];
            atomicOr(&flags[n >> 5], 1u << (n & 31));
        }
    }
    __syncthreads();
    int base = blockIdx.x * EPB;
    int lim = NUM_EDGES - base; if (lim > EPB) lim = EPB;
    for (int k = t; k < lim; k += 256)
        atomicAdd(&cnt[rows[base + k] >> 7], 1);
    __syncthreads();
    for (int i = t; i < NBUCK; i += 256) {
        int c = cnt[i];
        gbase[i] = c ? atomicAdd(&gcursor[i], c) : 0;
    }
    __syncthreads();
    for (int k = t; k < lim; k += 256) {
        int idx = base + k;
        int r = rows[idx];
        int b = r >> 7;
        int lofs = atomicAdd(&lcur[b], 1);
        unsigned long long packed =
            ((unsigned long long)(unsigned)__float_as_int(vals[idx]) << 32)
            | ((unsigned)(r & 127) << 17) | (unsigned)cols[idx];
        tmp[(size_t)b * CAP + gbase[b] + lofs] = packed;
    }
}

// ---------------------------------------------------------------------------
// 2) exclusive scan of bucket counts -> exact CSR bases
// ---------------------------------------------------------------------------
__global__ __launch_bounds__(1024) void bucket_scan(
    const int* __restrict__ gcursor, int* __restrict__ bbase, int* __restrict__ bcount)
{
    __shared__ int s[1024];
    int t = threadIdx.x;
    int c = (t < NBUCK) ? gcursor[t] : 0;
    s[t] = c;
    __syncthreads();
    #pragma unroll
    for (int off = 1; off < 1024; off <<= 1) {
        int x = (t >= off) ? s[t - off] : 0;
        __syncthreads();
        s[t] += x;
        __syncthreads();
    }
    if (t < NBUCK) {
        bbase[t]  = s[t] - c;
        bcount[t] = c;
    }
}

// ---------------------------------------------------------------------------
// 3) per-bucket counting sort by key (lrow<<4 | col>>13): row-contiguous CSR
//    whose per-row edge lists are col-tile-ordered (moving gather window).
//    Emits rse (start,end) per row + dense CSR. Coalesced write-out.
// ---------------------------------------------------------------------------
__global__ __launch_bounds__(256) void sort_buckets(
    const unsigned long long* __restrict__ tmp,
    const int* __restrict__ bbase, const int* __restrict__ bcount,
    int2* __restrict__ rse, int2* __restrict__ csr)
{
    __shared__ int cnt[NBINS], cur[NBINS];   // 16 KB
    __shared__ int sdata[256];
    __shared__ int2 stage[CAP];              // 16 KB
    int b = blockIdx.x;
    int t = threadIdx.x;
    int count = bcount[b];
    int base  = bbase[b];
    const unsigned long long* src = tmp + (size_t)b * CAP;
    for (int i = t; i < NBINS; i += 256) cnt[i] = 0;
    __syncthreads();
    // count by (lrow, col-tile)
    for (int i = t; i < count; i += 256) {
        unsigned long long v = src[i];
        int lrow = (int)((v >> 17) & 127);
        int ct   = (int)((v & 0x1FFFF) >> 13);
        atomicAdd(&cnt[(lrow << 4) | ct], 1);
    }
    __syncthreads();
    // scan 2048 bins: thread t owns bins 8t..8t+7
    int loc[8];
    int run = 0;
    #pragma unroll
    for (int j = 0; j < 8; ++j) { loc[j] = run; run += cnt[t * 8 + j]; }
    sdata[t] = run;
    __syncthreads();
    #pragma unroll
    for (int off = 1; off < 256; off <<= 1) {
        int x = (t >= off) ? sdata[t - off] : 0;
        __syncthreads();
        sdata[t] += x;
        __syncthreads();
    }
    int texcl = (t == 0) ? 0 : sdata[t - 1];
    #pragma unroll
    for (int j = 0; j < 8; ++j) cur[t * 8 + j] = texcl + loc[j];
    __syncthreads();
    // rse from bin bases (capture before scatter mutates cur)
    if (t < BROWS) {
        int st = cur[t << 4];
        int en = (t < BROWS - 1) ? cur[(t + 1) << 4] : count;
        int row = b * BROWS + t;
        if (row < NUM_NODES)
            rse[row] = make_int2(base + st, base + en);
    }
    __syncthreads();
    // scatter into stage
    for (int i = t; i < count; i += 256) {
        unsigned long long v = src[i];
        int lrow = (int)((v >> 17) & 127);
        int ct   = (int)((v & 0x1FFFF) >> 13);
        int pos = atomicAdd(&cur[(lrow << 4) | ct], 1);
        stage[pos] = make_int2((int)(v & 0x1FFFF), (int)(v >> 32));
    }
    __syncthreads();
    // coalesced write-out
    for (int i = t; i < count; i += 256)
        csr[(size_t)base + i] = stage[i];
}

// ---------------------------------------------------------------------------
// needed-rows list for layer 3
// ---------------------------------------------------------------------------
__global__ __launch_bounds__(256) void compact_rows(
    const unsigned* __restrict__ flags, int* __restrict__ list,
    int* __restrict__ nrows)
{
    int i = blockIdx.x * blockDim.x + threadIdx.x;
    if (i < NUM_NODES && ((flags[i >> 5] >> (i & 31)) & 1u)) {
        int pos = atomicAdd(nrows, 1);   // compiler wave-aggregates
        list[pos] = i;
    }
}

// ---------------------------------------------------------------------------
// SpMM row body: 16 lanes per row, float4 per lane, 4x pipelined gathers
// (round-6 structure: 24 VGPR, high occupancy)
// ---------------------------------------------------------------------------
__device__ __forceinline__ const float4* src_base(
    int c, const float4* __restrict__ xu, const float4* __restrict__ xi)
{
    return (c < NUM_USERS) ? xu + ((size_t)c << 4)
                           : xi + ((size_t)(c - NUM_USERS) << 4);
}

__device__ __forceinline__ void spmm_row(
    int row, int q, const int2* __restrict__ rse, const int2* __restrict__ csr,
    const float4* __restrict__ xu, const float4* __restrict__ xi,
    float* __restrict__ y)
{
    int2 se = rse[row];
    int e   = se.x;
    int end = se.y;
    float4 acc = make_float4(0.f, 0.f, 0.f, 0.f);
    for (; e + 3 < end; e += 4) {
        int2 p0 = csr[e], p1 = csr[e + 1], p2 = csr[e + 2], p3 = csr[e + 3];
        float4 x0 = src_base(p0.x, xu, xi)[q];
        float4 x1 = src_base(p1.x, xu, xi)[q];
        float4 x2 = src_base(p2.x, xu, xi)[q];
        float4 x3 = src_base(p3.x, xu, xi)[q];
        float v0 = __int_as_float(p0.y), v1 = __int_as_float(p1.y);
        float v2 = __int_as_float(p2.y), v3 = __int_as_float(p3.y);
        acc.x = fmaf(v0, x0.x, acc.x); acc.y = fmaf(v0, x0.y, acc.y);
        acc.z = fmaf(v0, x0.z, acc.z); acc.w = fmaf(v0, x0.w, acc.w);
        acc.x = fmaf(v1, x1.x, acc.x); acc.y = fmaf(v1, x1.y, acc.y);
        acc.z = fmaf(v1, x1.z, acc.z); acc.w = fmaf(v1, x1.w, acc.w);
        acc.x = fmaf(v2, x2.x, acc.x); acc.y = fmaf(v2, x2.y, acc.y);
        acc.z = fmaf(v2, x2.z, acc.z); acc.w = fmaf(v2, x2.w, acc.w);
        acc.x = fmaf(v3, x3.x, acc.x); acc.y = fmaf(v3, x3.y, acc.y);
        acc.z = fmaf(v3, x3.z, acc.z); acc.w = fmaf(v3, x3.w, acc.w);
    }
    for (; e < end; ++e) {
        int2 p0 = csr[e];
        float4 x0 = src_base(p0.x, xu, xi)[q];
        float v = __int_as_float(p0.y);
        acc.x = fmaf(v, x0.x, acc.x); acc.y = fmaf(v, x0.y, acc.y);
        acc.z = fmaf(v, x0.z, acc.z); acc.w = fmaf(v, x0.w, acc.w);
    }
    ((float4*)y)[((size_t)row << 4) + q] = acc;
}

// dense-row SpMM (layers 1 & 2)
__global__ __launch_bounds__(256) void spmm_csr(
    const int2* __restrict__ rse, const int2* __restrict__ csr,
    const float* __restrict__ xu, const float* __restrict__ xi,
    float* __restrict__ y)
{
    int tid = blockIdx.x * blockDim.x + threadIdx.x;
    int row = tid >> 4;
    if (row >= NUM_NODES) return;
    spmm_row(row, tid & 15, rse, csr, (const float4*)xu, (const float4*)xi, y);
}

// listed-row SpMM (layer 3: only rows the dot reads)
__global__ __launch_bounds__(256) void spmm_csr_list(
    const int* __restrict__ list, const int* __restrict__ nrows,
    const int2* __restrict__ rse, const int2* __restrict__ csr,
    const float* __restrict__ x, float* __restrict__ y)
{
    int tid = blockIdx.x * blockDim.x + threadIdx.x;
    int i = tid >> 4;
    if (i >= *nrows) return;
    const float4* xb = (const float4*)x;
    spmm_row(list[i], tid & 15, rse, csr, xb, xb + ((size_t)NUM_USERS << 4), y);
}

// ---------------------------------------------------------------------------
// batched dot: one wave per batch element
// ---------------------------------------------------------------------------
__global__ __launch_bounds__(256) void dot_kernel(
    const int*   __restrict__ uidx,
    const int*   __restrict__ iidx,
    const float* __restrict__ x,
    float*       __restrict__ out)
{
    int wid  = (blockIdx.x * blockDim.x + threadIdx.x) >> 6;
    int lane = threadIdx.x & 63;
    if (wid >= BATCH) return;
    int u  = uidx[wid];
    int it = iidx[wid];
    float a = x[(size_t)u * DIM + lane];
    float bb = x[((size_t)NUM_USERS + it) * DIM + lane];
    float p = a * bb;
    #pragma unroll
    for (int off = 32; off > 0; off >>= 1)
        p += __shfl_down(p, off);
    if (lane == 0) out[wid] = p;
}

extern "C" void kernel_launch(void* const* d_in, const int* in_sizes, int n_in,
                              void* d_out, int out_size, void* d_ws, size_t ws_size,
                              hipStream_t stream)
{
    const int*   user_indices = (const int*)  d_in[0];
    const int*   item_indices = (const int*)  d_in[1];
    const int*   edge_rows    = (const int*)  d_in[2];
    const int*   edge_cols    = (const int*)  d_in[3];
    const float* edge_vals    = (const float*)d_in[4];
    const float* user_emb     = (const float*)d_in[5];
    const float* item_emb     = (const float*)d_in[6];
    float*       out          = (float*)      d_out;

    // ---- workspace layout ----
    const size_t nfloats = (size_t)NUM_NODES * DIM;   // 6.4M floats
    char* p = (char*)d_ws;
    unsigned long long* tmp = (unsigned long long*)p;
    p += (size_t)NBUCK * CAP * 8;                     // 12.8 MB
    float*    bufA    = (float*)p;    p += nfloats * 4;   // 25.6 MB
    float*    bufB    = (float*)p;    p += nfloats * 4;   // 25.6 MB
    int2*     rse     = (int2*)p;     p += 102400 * 8;
    int*      gcursor = (int*)p;      p += 1024 * 4;
    int*      bbase   = (int*)p;      p += 1024 * 4;
    int*      bcount  = (int*)p;      p += 1024 * 4;
    int*      nrows   = (int*)p;      p += 256 * 4;
    unsigned* flags   = (unsigned*)p; p += 3200 * 4;      // 100K bits (+pad)
    int*      rowlist = (int*)p;      p += 33024 * 4;     // <= 32768 rows
    int2*     csr     = (int2*)p;     p += (size_t)NUM_EDGES * 8;   // 9.6 MB

    const int NB_BIN = (NUM_EDGES + EPB - 1) / EPB;   // 293

    // ---- clear cursors + nrows + flags (one contiguous memset region) ----
    hipMemsetAsync(gcursor, 0, (1024 + 1024 + 1024 + 256 + 3200) * sizeof(int), stream);
    bin_edges<<<NB_BIN, 256, 0, stream>>>(
        edge_rows, edge_cols, edge_vals, user_indices, item_indices,
        gcursor, flags, tmp);
    bucket_scan<<<1, 1024, 0, stream>>>(gcursor, bbase, bcount);
    sort_buckets<<<NBUCK, 256, 0, stream>>>(tmp, bbase, bcount, rse, csr);
    compact_rows<<<(NUM_NODES + 255) / 256, 256, 0, stream>>>(
        flags, rowlist, nrows);

    // ---- 3 SpMM layers (layer 1 fuses concat; layer 3 listed rows) ----
    const int NB_SPMM = (NUM_NODES * 16 + 255) / 256;   // 6250
    spmm_csr<<<NB_SPMM, 256, 0, stream>>>(rse, csr, user_emb, item_emb, bufB);
    spmm_csr<<<NB_SPMM, 256, 0, stream>>>(rse, csr, bufB, bufB + (size_t)NUM_USERS * DIM, bufA);
    spmm_csr_list<<<(32768 * 16) / 256, 256, 0, stream>>>(
        rowlist, nrows, rse, csr, bufA, bufB);

    // ---- final dot ----
    dot_kernel<<<(BATCH * 64) / 256, 256, 0, stream>>>(
        user_indices, item_indices, bufB, out);
}

// Round 11
// 157.233 us; speedup vs baseline: 9.2006x; 1.1246x over previous
//
#include <hip/hip_runtime.h>

#define NUM_USERS 60000
#define NUM_ITEMS 40000
#define NUM_NODES 100000
#define DIM       64
#define NUM_EDGES 1200000
#define BATCH     16384

#define BROWS 128                 // rows per bucket
#define NBUCK 782                 // ceil(100000/128)
#define CAP   2048                // padded slots per bucket (mean 1536, +13 sigma)
#define EPB   4096                // edges per bin_edges block -> 293 blocks
#define NBINS 2048                // 128 rows x 16 col-tile slots
#define NFLAGW 3125               // 100000 bits in u32 words

// ---------------------------------------------------------------------------
// 1) bin edges into 782 row-buckets (padded, cursors start at 0) + fused
//    batch-row flagging. Packed u64: [val:32][lrow:7][col:17]
// ---------------------------------------------------------------------------
__global__ __launch_bounds__(256) void bin_edges(
    const int* __restrict__ rows, const int* __restrict__ cols,
    const float* __restrict__ vals,
    const int* __restrict__ uidx, const int* __restrict__ iidx,
    int* __restrict__ gcursor, unsigned* __restrict__ flags,
    unsigned long long* __restrict__ tmp)
{
    __shared__ int cnt[NBUCK], lcur[NBUCK], gbase[NBUCK];
    int t = threadIdx.x;
    for (int i = t; i < NBUCK; i += 256) { cnt[i] = 0; lcur[i] = 0; }
    int fbase = blockIdx.x * 112;
    for (int k = t; k < 112; k += 256) {
        int gi = fbase + k;
        if (gi < BATCH) {
            int n = uidx[gi];
            atomicOr(&flags[n >> 5], 1u << (n & 31));
        } else if (gi < 2 * BATCH) {
            int n = NUM_USERS + iidx[gi - BATCH];
            atomicOr(&flags[n >> 5], 1u << (n & 31));
        }
    }
    __syncthreads();
    int base = blockIdx.x * EPB;
    int lim = NUM_EDGES - base; if (lim > EPB) lim = EPB;
    for (int k = t; k < lim; k += 256)
        atomicAdd(&cnt[rows[base + k] >> 7], 1);
    __syncthreads();
    for (int i = t; i < NBUCK; i += 256) {
        int c = cnt[i];
        gbase[i] = c ? atomicAdd(&gcursor[i], c) : 0;
    }
    __syncthreads();
    for (int k = t; k < lim; k += 256) {
        int idx = base + k;
        int r = rows[idx];
        int b = r >> 7;
        int lofs = atomicAdd(&lcur[b], 1);
        unsigned long long packed =
            ((unsigned long long)(unsigned)__float_as_int(vals[idx]) << 32)
            | ((unsigned)(r & 127) << 17) | (unsigned)cols[idx];
        tmp[(size_t)b * CAP + gbase[b] + lofs] = packed;
    }
}

// ---------------------------------------------------------------------------
// 2) exclusive scan of bucket counts -> exact CSR bases
// ---------------------------------------------------------------------------
__global__ __launch_bounds__(1024) void bucket_scan(
    const int* __restrict__ gcursor, int* __restrict__ bbase, int* __restrict__ bcount)
{
    __shared__ int s[1024];
    int t = threadIdx.x;
    int c = (t < NBUCK) ? gcursor[t] : 0;
    s[t] = c;
    __syncthreads();
    #pragma unroll
    for (int off = 1; off < 1024; off <<= 1) {
        int x = (t >= off) ? s[t - off] : 0;
        __syncthreads();
        s[t] += x;
        __syncthreads();
    }
    if (t < NBUCK) {
        bbase[t]  = s[t] - c;
        bcount[t] = c;
    }
}

// ---------------------------------------------------------------------------
// 3) per-bucket counting sort by (lrow<<4 | col>>13) -> rse + dense CSR
// ---------------------------------------------------------------------------
__global__ __launch_bounds__(256) void sort_buckets(
    const unsigned long long* __restrict__ tmp,
    const int* __restrict__ bbase, const int* __restrict__ bcount,
    int2* __restrict__ rse, int2* __restrict__ csr)
{
    __shared__ int cnt[NBINS], cur[NBINS];
    __shared__ int sdata[256];
    __shared__ int2 stage[CAP];
    int b = blockIdx.x;
    int t = threadIdx.x;
    int count = bcount[b];
    int base  = bbase[b];
    const unsigned long long* src = tmp + (size_t)b * CAP;
    for (int i = t; i < NBINS; i += 256) cnt[i] = 0;
    __syncthreads();
    for (int i = t; i < count; i += 256) {
        unsigned long long v = src[i];
        int lrow = (int)((v >> 17) & 127);
        int ct   = (int)((v & 0x1FFFF) >> 13);
        atomicAdd(&cnt[(lrow << 4) | ct], 1);
    }
    __syncthreads();
    int loc[8];
    int run = 0;
    #pragma unroll
    for (int j = 0; j < 8; ++j) { loc[j] = run; run += cnt[t * 8 + j]; }
    sdata[t] = run;
    __syncthreads();
    #pragma unroll
    for (int off = 1; off < 256; off <<= 1) {
        int x = (t >= off) ? sdata[t - off] : 0;
        __syncthreads();
        sdata[t] += x;
        __syncthreads();
    }
    int texcl = (t == 0) ? 0 : sdata[t - 1];
    #pragma unroll
    for (int j = 0; j < 8; ++j) cur[t * 8 + j] = texcl + loc[j];
    __syncthreads();
    if (t < BROWS) {
        int st = cur[t << 4];
        int en = (t < BROWS - 1) ? cur[(t + 1) << 4] : count;
        int row = b * BROWS + t;
        if (row < NUM_NODES)
            rse[row] = make_int2(base + st, base + en);
    }
    __syncthreads();
    for (int i = t; i < count; i += 256) {
        unsigned long long v = src[i];
        int lrow = (int)((v >> 17) & 127);
        int ct   = (int)((v & 0x1FFFF) >> 13);
        int pos = atomicAdd(&cur[(lrow << 4) | ct], 1);
        stage[pos] = make_int2((int)(v & 0x1FFFF), (int)(v >> 32));
    }
    __syncthreads();
    for (int i = t; i < count; i += 256)
        csr[(size_t)base + i] = stage[i];
}

// ---------------------------------------------------------------------------
// needed-rows list for layer 3
// ---------------------------------------------------------------------------
__global__ __launch_bounds__(256) void compact_rows(
    const unsigned* __restrict__ flags, int* __restrict__ list,
    int* __restrict__ nrows)
{
    int i = blockIdx.x * blockDim.x + threadIdx.x;
    if (i < NUM_NODES && ((flags[i >> 5] >> (i & 31)) & 1u)) {
        int pos = atomicAdd(nrows, 1);
        list[pos] = i;
    }
}

// ---------------------------------------------------------------------------
// helpers: bf16 pack/unpack, gathers, accumulate loop
// ---------------------------------------------------------------------------
__device__ __forceinline__ unsigned short f2bf(float f) {
    unsigned u = __float_as_uint(f);
    unsigned r = (u + 0x7FFFu + ((u >> 16) & 1u)) >> 16;   // RNE
    return (unsigned short)r;
}

template<typename G>
__device__ __forceinline__ float4 row_accum(
    int e, int end, int q, const int2* __restrict__ csr, G g)
{
    float4 acc = make_float4(0.f, 0.f, 0.f, 0.f);
    for (; e + 3 < end; e += 4) {
        int2 p0 = csr[e], p1 = csr[e + 1], p2 = csr[e + 2], p3 = csr[e + 3];
        float4 x0 = g(p0.x, q);
        float4 x1 = g(p1.x, q);
        float4 x2 = g(p2.x, q);
        float4 x3 = g(p3.x, q);
        float v0 = __int_as_float(p0.y), v1 = __int_as_float(p1.y);
        float v2 = __int_as_float(p2.y), v3 = __int_as_float(p3.y);
        acc.x = fmaf(v0, x0.x, acc.x); acc.y = fmaf(v0, x0.y, acc.y);
        acc.z = fmaf(v0, x0.z, acc.z); acc.w = fmaf(v0, x0.w, acc.w);
        acc.x = fmaf(v1, x1.x, acc.x); acc.y = fmaf(v1, x1.y, acc.y);
        acc.z = fmaf(v1, x1.z, acc.z); acc.w = fmaf(v1, x1.w, acc.w);
        acc.x = fmaf(v2, x2.x, acc.x); acc.y = fmaf(v2, x2.y, acc.y);
        acc.z = fmaf(v2, x2.z, acc.z); acc.w = fmaf(v2, x2.w, acc.w);
        acc.x = fmaf(v3, x3.x, acc.x); acc.y = fmaf(v3, x3.y, acc.y);
        acc.z = fmaf(v3, x3.z, acc.z); acc.w = fmaf(v3, x3.w, acc.w);
    }
    for (; e < end; ++e) {
        int2 p0 = csr[e];
        float4 x0 = g(p0.x, q);
        float v = __int_as_float(p0.y);
        acc.x = fmaf(v, x0.x, acc.x); acc.y = fmaf(v, x0.y, acc.y);
        acc.z = fmaf(v, x0.z, acc.z); acc.w = fmaf(v, x0.w, acc.w);
    }
    return acc;
}

__device__ __forceinline__ void store_bf16(
    unsigned short* __restrict__ y16, int row, int q, float4 a)
{
    ushort4 s;
    s.x = f2bf(a.x); s.y = f2bf(a.y); s.z = f2bf(a.z); s.w = f2bf(a.w);
    *(ushort4*)(y16 + ((size_t)row << 6) + (q << 2)) = s;
}

// ---------------------------------------------------------------------------
// layer 1: dense, fp32 gather from split user/item embeddings, bf16 out
// ---------------------------------------------------------------------------
__global__ __launch_bounds__(256) void spmm_l1(
    const int2* __restrict__ rse, const int2* __restrict__ csr,
    const float* __restrict__ ue, const float* __restrict__ ie,
    unsigned short* __restrict__ y16)
{
    int tid = blockIdx.x * blockDim.x + threadIdx.x;
    int row = tid >> 4;
    if (row >= NUM_NODES) return;
    int q = tid & 15;
    const float4* xu = (const float4*)ue;
    const float4* xi = (const float4*)ie;
    int2 se = rse[row];
    float4 acc = row_accum(se.x, se.y, q, csr,
        [xu, xi](int c, int qq) {
            const float4* s = (c < NUM_USERS)
                ? xu + ((size_t)c << 4)
                : xi + ((size_t)(c - NUM_USERS) << 4);
            return s[qq];
        });
    store_bf16(y16, row, q, acc);
}

// ---------------------------------------------------------------------------
// layer 2: dense, bf16 gather, bf16 out
// ---------------------------------------------------------------------------
__global__ __launch_bounds__(256) void spmm_l2(
    const int2* __restrict__ rse, const int2* __restrict__ csr,
    const unsigned short* __restrict__ x16, unsigned short* __restrict__ y16)
{
    int tid = blockIdx.x * blockDim.x + threadIdx.x;
    int row = tid >> 4;
    if (row >= NUM_NODES) return;
    int q = tid & 15;
    int2 se = rse[row];
    float4 acc = row_accum(se.x, se.y, q, csr,
        [x16](int c, int qq) {
            ushort4 h = *(const ushort4*)(x16 + ((size_t)c << 6) + (qq << 2));
            float4 f;
            f.x = __uint_as_float((unsigned)h.x << 16);
            f.y = __uint_as_float((unsigned)h.y << 16);
            f.z = __uint_as_float((unsigned)h.z << 16);
            f.w = __uint_as_float((unsigned)h.w << 16);
            return f;
        });
    store_bf16(y16, row, q, acc);
}

// ---------------------------------------------------------------------------
// layer 3: listed rows only, bf16 gather, fp32 out
// ---------------------------------------------------------------------------
__global__ __launch_bounds__(256) void spmm_l3(
    const int* __restrict__ list, const int* __restrict__ nrows,
    const int2* __restrict__ rse, const int2* __restrict__ csr,
    const unsigned short* __restrict__ x16, float* __restrict__ y)
{
    int tid = blockIdx.x * blockDim.x + threadIdx.x;
    int i = tid >> 4;
    if (i >= *nrows) return;
    int q = tid & 15;
    int row = list[i];
    int2 se = rse[row];
    float4 acc = row_accum(se.x, se.y, q, csr,
        [x16](int c, int qq) {
            ushort4 h = *(const ushort4*)(x16 + ((size_t)c << 6) + (qq << 2));
            float4 f;
            f.x = __uint_as_float((unsigned)h.x << 16);
            f.y = __uint_as_float((unsigned)h.y << 16);
            f.z = __uint_as_float((unsigned)h.z << 16);
            f.w = __uint_as_float((unsigned)h.w << 16);
            return f;
        });
    ((float4*)y)[((size_t)row << 4) + q] = acc;
}

// ---------------------------------------------------------------------------
// batched dot: one wave per batch element
// ---------------------------------------------------------------------------
__global__ __launch_bounds__(256) void dot_kernel(
    const int*   __restrict__ uidx,
    const int*   __restrict__ iidx,
    const float* __restrict__ x,
    float*       __restrict__ out)
{
    int wid  = (blockIdx.x * blockDim.x + threadIdx.x) >> 6;
    int lane = threadIdx.x & 63;
    if (wid >= BATCH) return;
    int u  = uidx[wid];
    int it = iidx[wid];
    float a = x[(size_t)u * DIM + lane];
    float bb = x[((size_t)NUM_USERS + it) * DIM + lane];
    float p = a * bb;
    #pragma unroll
    for (int off = 32; off > 0; off >>= 1)
        p += __shfl_down(p, off);
    if (lane == 0) out[wid] = p;
}

extern "C" void kernel_launch(void* const* d_in, const int* in_sizes, int n_in,
                              void* d_out, int out_size, void* d_ws, size_t ws_size,
                              hipStream_t stream)
{
    const int*   user_indices = (const int*)  d_in[0];
    const int*   item_indices = (const int*)  d_in[1];
    const int*   edge_rows    = (const int*)  d_in[2];
    const int*   edge_cols    = (const int*)  d_in[3];
    const float* edge_vals    = (const float*)d_in[4];
    const float* user_emb     = (const float*)d_in[5];
    const float* item_emb     = (const float*)d_in[6];
    float*       out          = (float*)      d_out;

    // ---- workspace layout ----
    const size_t nfloats = (size_t)NUM_NODES * DIM;   // 6.4M elements
    char* p = (char*)d_ws;
    unsigned long long* tmp = (unsigned long long*)p;
    p += (size_t)NBUCK * CAP * 8;                       // 12.8 MB
    float*          bufA  = (float*)p;          p += nfloats * 4;   // 25.6 MB (L3 out)
    unsigned short* b16A  = (unsigned short*)p; p += nfloats * 2;   // 12.8 MB (L1 out)
    unsigned short* b16B  = (unsigned short*)p; p += nfloats * 2;   // 12.8 MB (L2 out)
    int2*     rse     = (int2*)p;     p += 102400 * 8;
    int*      gcursor = (int*)p;      p += 1024 * 4;
    int*      bbase   = (int*)p;      p += 1024 * 4;
    int*      bcount  = (int*)p;      p += 1024 * 4;
    int*      nrows   = (int*)p;      p += 256 * 4;
    unsigned* flags   = (unsigned*)p; p += 3200 * 4;
    int*      rowlist = (int*)p;      p += 33024 * 4;
    int2*     csr     = (int2*)p;     p += (size_t)NUM_EDGES * 8;   // 9.6 MB

    const int NB_BIN = (NUM_EDGES + EPB - 1) / EPB;   // 293

    // ---- clear cursors + scan bufs + nrows + flags (one contiguous memset) ----
    hipMemsetAsync(gcursor, 0, (1024 + 1024 + 1024 + 256 + 3200) * sizeof(int), stream);
    bin_edges<<<NB_BIN, 256, 0, stream>>>(
        edge_rows, edge_cols, edge_vals, user_indices, item_indices,
        gcursor, flags, tmp);
    bucket_scan<<<1, 1024, 0, stream>>>(gcursor, bbase, bcount);
    sort_buckets<<<NBUCK, 256, 0, stream>>>(tmp, bbase, bcount, rse, csr);
    compact_rows<<<(NUM_NODES + 255) / 256, 256, 0, stream>>>(
        flags, rowlist, nrows);

    // ---- 3 SpMM layers: fp32->bf16, bf16->bf16, bf16->fp32(listed) ----
    const int NB_SPMM = (NUM_NODES * 16 + 255) / 256;   // 6250
    spmm_l1<<<NB_SPMM, 256, 0, stream>>>(rse, csr, user_emb, item_emb, b16A);
    spmm_l2<<<NB_SPMM, 256, 0, stream>>>(rse, csr, b16A, b16B);
    spmm_l3<<<(32768 * 16) / 256, 256, 0, stream>>>(
        rowlist, nrows, rse, csr, b16B, bufA);

    // ---- final dot ----
    dot_kernel<<<(BATCH * 64) / 256, 256, 0, stream>>>(
        user_indices, item_indices, bufA, out);
}

// Round 13
// 147.438 us; speedup vs baseline: 9.8118x; 1.0664x over previous
//
#include <hip/hip_runtime.h>

#define NUM_USERS 60000
#define NUM_ITEMS 40000
#define NUM_NODES 100000
#define DIM       64
#define NUM_EDGES 1200000
#define BATCH     16384

#define BROWS 128                 // rows per bucket
#define NBUCK 782                 // ceil(100000/128)
#define CAP   2048                // padded slots per bucket (mean 1536, +13 sigma)
#define EPB   4096                // edges per bin_edges block -> 293 blocks
#define NBINS 2048                // 128 rows x 16 col-tile slots
#define NFLAGW 3125               // 100000 bits in u32 words

// ---------------------------------------------------------------------------
// 0) convert fp32 user/item embeddings -> one concatenated bf16 buffer
// ---------------------------------------------------------------------------
__device__ __forceinline__ unsigned short f2bf(float f) {
    unsigned u = __float_as_uint(f);
    unsigned r = (u + 0x7FFFu + ((u >> 16) & 1u)) >> 16;   // RNE
    return (unsigned short)r;
}

__global__ __launch_bounds__(256) void convert_emb(
    const float4* __restrict__ ue, const float4* __restrict__ ie,
    ushort4* __restrict__ xc)
{
    const int nU4 = NUM_USERS * (DIM / 4);       // 960000
    const int total4 = NUM_NODES * (DIM / 4);    // 1600000
    int i = blockIdx.x * blockDim.x + threadIdx.x;
    int stride = gridDim.x * blockDim.x;
    for (; i < total4; i += stride) {
        float4 v = (i < nU4) ? ue[i] : ie[i - nU4];
        ushort4 s;
        s.x = f2bf(v.x); s.y = f2bf(v.y); s.z = f2bf(v.z); s.w = f2bf(v.w);
        xc[i] = s;
    }
}

// ---------------------------------------------------------------------------
// 1) bin edges into 782 row-buckets (padded, cursors start at 0) + fused
//    batch-row flagging. Packed u64: [val:32][lrow:7][col:17]
// ---------------------------------------------------------------------------
__global__ __launch_bounds__(256) void bin_edges(
    const int* __restrict__ rows, const int* __restrict__ cols,
    const float* __restrict__ vals,
    const int* __restrict__ uidx, const int* __restrict__ iidx,
    int* __restrict__ gcursor, unsigned* __restrict__ flags,
    unsigned long long* __restrict__ tmp)
{
    __shared__ int cnt[NBUCK], lcur[NBUCK], gbase[NBUCK];
    int t = threadIdx.x;
    for (int i = t; i < NBUCK; i += 256) { cnt[i] = 0; lcur[i] = 0; }
    int fbase = blockIdx.x * 112;
    for (int k = t; k < 112; k += 256) {
        int gi = fbase + k;
        if (gi < BATCH) {
            int n = uidx[gi];
            atomicOr(&flags[n >> 5], 1u << (n & 31));
        } else if (gi < 2 * BATCH) {
            int n = NUM_USERS + iidx[gi - BATCH];
            atomicOr(&flags[n >> 5], 1u << (n & 31));
        }
    }
    __syncthreads();
    int base = blockIdx.x * EPB;
    int lim = NUM_EDGES - base; if (lim > EPB) lim = EPB;
    for (int k = t; k < lim; k += 256)
        atomicAdd(&cnt[rows[base + k] >> 7], 1);
    __syncthreads();
    for (int i = t; i < NBUCK; i += 256) {
        int c = cnt[i];
        gbase[i] = c ? atomicAdd(&gcursor[i], c) : 0;
    }
    __syncthreads();
    for (int k = t; k < lim; k += 256) {
        int idx = base + k;
        int r = rows[idx];
        int b = r >> 7;
        int lofs = atomicAdd(&lcur[b], 1);
        unsigned long long packed =
            ((unsigned long long)(unsigned)__float_as_int(vals[idx]) << 32)
            | ((unsigned)(r & 127) << 17) | (unsigned)cols[idx];
        tmp[(size_t)b * CAP + gbase[b] + lofs] = packed;
    }
}

// ---------------------------------------------------------------------------
// 2) per-bucket counting sort by (lrow<<4 | col>>13) -> rse + padded CSR
//    (CSR lives at b*CAP: no global scan needed)
// ---------------------------------------------------------------------------
__global__ __launch_bounds__(256) void sort_buckets(
    const unsigned long long* __restrict__ tmp, const int* __restrict__ gcursor,
    int2* __restrict__ rse, int2* __restrict__ csr)
{
    __shared__ int cnt[NBINS], cur[NBINS];
    __shared__ int sdata[256];
    __shared__ int2 stage[CAP];
    int b = blockIdx.x;
    int t = threadIdx.x;
    int count = gcursor[b];
    int base  = b * CAP;
    const unsigned long long* src = tmp + (size_t)base;
    for (int i = t; i < NBINS; i += 256) cnt[i] = 0;
    __syncthreads();
    for (int i = t; i < count; i += 256) {
        unsigned long long v = src[i];
        int lrow = (int)((v >> 17) & 127);
        int ct   = (int)((v & 0x1FFFF) >> 13);
        atomicAdd(&cnt[(lrow << 4) | ct], 1);
    }
    __syncthreads();
    int loc[8];
    int run = 0;
    #pragma unroll
    for (int j = 0; j < 8; ++j) { loc[j] = run; run += cnt[t * 8 + j]; }
    sdata[t] = run;
    __syncthreads();
    #pragma unroll
    for (int off = 1; off < 256; off <<= 1) {
        int x = (t >= off) ? sdata[t - off] : 0;
        __syncthreads();
        sdata[t] += x;
        __syncthreads();
    }
    int texcl = (t == 0) ? 0 : sdata[t - 1];
    #pragma unroll
    for (int j = 0; j < 8; ++j) cur[t * 8 + j] = texcl + loc[j];
    __syncthreads();
    if (t < BROWS) {
        int st = cur[t << 4];
        int en = (t < BROWS - 1) ? cur[(t + 1) << 4] : count;
        int row = b * BROWS + t;
        if (row < NUM_NODES)
            rse[row] = make_int2(base + st, base + en);
    }
    __syncthreads();
    for (int i = t; i < count; i += 256) {
        unsigned long long v = src[i];
        int lrow = (int)((v >> 17) & 127);
        int ct   = (int)((v & 0x1FFFF) >> 13);
        int pos = atomicAdd(&cur[(lrow << 4) | ct], 1);
        stage[pos] = make_int2((int)(v & 0x1FFFF), (int)(v >> 32));
    }
    __syncthreads();
    for (int i = t; i < count; i += 256)
        csr[(size_t)base + i] = stage[i];
}

// ---------------------------------------------------------------------------
// needed-rows list for layer 3
// ---------------------------------------------------------------------------
__global__ __launch_bounds__(256) void compact_rows(
    const unsigned* __restrict__ flags, int* __restrict__ list,
    int* __restrict__ nrows)
{
    int i = blockIdx.x * blockDim.x + threadIdx.x;
    if (i < NUM_NODES && ((flags[i >> 5] >> (i & 31)) & 1u)) {
        int pos = atomicAdd(nrows, 1);
        list[pos] = i;
    }
}

// ---------------------------------------------------------------------------
// bf16 gather + row accumulate (16 lanes/row, ushort4 per lane, 4x unroll)
// ---------------------------------------------------------------------------
__device__ __forceinline__ float4 bf16_row(const unsigned short* x16, int c, int q)
{
    ushort4 h = *(const ushort4*)(x16 + ((size_t)c << 6) + (q << 2));
    float4 f;
    f.x = __uint_as_float((unsigned)h.x << 16);
    f.y = __uint_as_float((unsigned)h.y << 16);
    f.z = __uint_as_float((unsigned)h.z << 16);
    f.w = __uint_as_float((unsigned)h.w << 16);
    return f;
}

__device__ __forceinline__ float4 row_accum_bf16(
    int e, int end, int q, const int2* __restrict__ csr,
    const unsigned short* __restrict__ x16)
{
    float4 acc = make_float4(0.f, 0.f, 0.f, 0.f);
    for (; e + 3 < end; e += 4) {
        int2 p0 = csr[e], p1 = csr[e + 1], p2 = csr[e + 2], p3 = csr[e + 3];
        float4 x0 = bf16_row(x16, p0.x, q);
        float4 x1 = bf16_row(x16, p1.x, q);
        float4 x2 = bf16_row(x16, p2.x, q);
        float4 x3 = bf16_row(x16, p3.x, q);
        float v0 = __int_as_float(p0.y), v1 = __int_as_float(p1.y);
        float v2 = __int_as_float(p2.y), v3 = __int_as_float(p3.y);
        acc.x = fmaf(v0, x0.x, acc.x); acc.y = fmaf(v0, x0.y, acc.y);
        acc.z = fmaf(v0, x0.z, acc.z); acc.w = fmaf(v0, x0.w, acc.w);
        acc.x = fmaf(v1, x1.x, acc.x); acc.y = fmaf(v1, x1.y, acc.y);
        acc.z = fmaf(v1, x1.z, acc.z); acc.w = fmaf(v1, x1.w, acc.w);
        acc.x = fmaf(v2, x2.x, acc.x); acc.y = fmaf(v2, x2.y, acc.y);
        acc.z = fmaf(v2, x2.z, acc.z); acc.w = fmaf(v2, x2.w, acc.w);
        acc.x = fmaf(v3, x3.x, acc.x); acc.y = fmaf(v3, x3.y, acc.y);
        acc.z = fmaf(v3, x3.z, acc.z); acc.w = fmaf(v3, x3.w, acc.w);
    }
    for (; e < end; ++e) {
        int2 p0 = csr[e];
        float4 x0 = bf16_row(x16, p0.x, q);
        float v = __int_as_float(p0.y);
        acc.x = fmaf(v, x0.x, acc.x); acc.y = fmaf(v, x0.y, acc.y);
        acc.z = fmaf(v, x0.z, acc.z); acc.w = fmaf(v, x0.w, acc.w);
    }
    return acc;
}

// dense layer: bf16 in, bf16 out (used for layers 1 and 2)
__global__ __launch_bounds__(256) void spmm_bb(
    const int2* __restrict__ rse, const int2* __restrict__ csr,
    const unsigned short* __restrict__ x16, unsigned short* __restrict__ y16)
{
    int tid = blockIdx.x * blockDim.x + threadIdx.x;
    int row = tid >> 4;
    if (row >= NUM_NODES) return;
    int q = tid & 15;
    int2 se = rse[row];
    float4 a = row_accum_bf16(se.x, se.y, q, csr, x16);
    ushort4 s;
    s.x = f2bf(a.x); s.y = f2bf(a.y); s.z = f2bf(a.z); s.w = f2bf(a.w);
    *(ushort4*)(y16 + ((size_t)row << 6) + (q << 2)) = s;
}

// layer 3: listed rows only, bf16 in, fp32 out
__global__ __launch_bounds__(256) void spmm_l3(
    const int* __restrict__ list, const int* __restrict__ nrows,
    const int2* __restrict__ rse, const int2* __restrict__ csr,
    const unsigned short* __restrict__ x16, float* __restrict__ y)
{
    int tid = blockIdx.x * blockDim.x + threadIdx.x;
    int i = tid >> 4;
    if (i >= *nrows) return;
    int q = tid & 15;
    int row = list[i];
    int2 se = rse[row];
    float4 acc = row_accum_bf16(se.x, se.y, q, csr, x16);
    ((float4*)y)[((size_t)row << 4) + q] = acc;
}

// ---------------------------------------------------------------------------
// batched dot: one wave per batch element
// ---------------------------------------------------------------------------
__global__ __launch_bounds__(256) void dot_kernel(
    const int*   __restrict__ uidx,
    const int*   __restrict__ iidx,
    const float* __restrict__ x,
    float*       __restrict__ out)
{
    int wid  = (blockIdx.x * blockDim.x + threadIdx.x) >> 6;
    int lane = threadIdx.x & 63;
    if (wid >= BATCH) return;
    int u  = uidx[wid];
    int it = iidx[wid];
    float a = x[(size_t)u * DIM + lane];
    float bb = x[((size_t)NUM_USERS + it) * DIM + lane];
    float p = a * bb;
    #pragma unroll
    for (int off = 32; off > 0; off >>= 1)
        p += __shfl_down(p, off);
    if (lane == 0) out[wid] = p;
}

extern "C" void kernel_launch(void* const* d_in, const int* in_sizes, int n_in,
                              void* d_out, int out_size, void* d_ws, size_t ws_size,
                              hipStream_t stream)
{
    const int*   user_indices = (const int*)  d_in[0];
    const int*   item_indices = (const int*)  d_in[1];
    const int*   edge_rows    = (const int*)  d_in[2];
    const int*   edge_cols    = (const int*)  d_in[3];
    const float* edge_vals    = (const float*)d_in[4];
    const float* user_emb     = (const float*)d_in[5];
    const float* item_emb     = (const float*)d_in[6];
    float*       out          = (float*)      d_out;

    // ---- workspace layout ----
    // Liveness-safe alias: bufA (l3 fp32 out, 25.6 MB) overlays tmp (dead after
    // sort_buckets) + xc (dead after layer 1). l3 reads b16A, which is disjoint.
    const size_t nfloats = (size_t)NUM_NODES * DIM;   // 6.4M elements
    char* p = (char*)d_ws;
    float* bufA = (float*)p;                            // 25.6 MB span (alias)
    unsigned long long* tmp = (unsigned long long*)p;
    p += (size_t)NBUCK * CAP * 8;                       // 12.8 MB
    unsigned short* xc   = (unsigned short*)p;  p += nfloats * 2;   // 12.8 MB
    unsigned short* b16B = (unsigned short*)p;  p += nfloats * 2;   // 12.8 MB
    unsigned short* b16A = (unsigned short*)p;  p += nfloats * 2;   // 12.8 MB
    int2*     rse     = (int2*)p;     p += 102400 * 8;
    int*      gcursor = (int*)p;      p += 1024 * 4;
    int*      nrows   = (int*)p;      p += 256 * 4;
    unsigned* flags   = (unsigned*)p; p += 3200 * 4;
    int*      rowlist = (int*)p;      p += 33024 * 4;
    int2*     csr     = (int2*)p;     p += (size_t)NBUCK * CAP * 8; // 12.8 MB (padded)

    const int NB_BIN = (NUM_EDGES + EPB - 1) / EPB;   // 293

    // ---- clear cursors + nrows + flags (one contiguous memset) ----
    hipMemsetAsync(gcursor, 0, (1024 + 256 + 3200) * sizeof(int), stream);
    convert_emb<<<2048, 256, 0, stream>>>(
        (const float4*)user_emb, (const float4*)item_emb, (ushort4*)xc);
    bin_edges<<<NB_BIN, 256, 0, stream>>>(
        edge_rows, edge_cols, edge_vals, user_indices, item_indices,
        gcursor, flags, tmp);
    sort_buckets<<<NBUCK, 256, 0, stream>>>(tmp, gcursor, rse, csr);
    compact_rows<<<(NUM_NODES + 255) / 256, 256, 0, stream>>>(
        flags, rowlist, nrows);

    // ---- 3 SpMM layers: bf16->bf16, bf16->bf16, bf16->fp32(listed) ----
    const int NB_SPMM = (NUM_NODES * 16 + 255) / 256;   // 6250
    spmm_bb<<<NB_SPMM, 256, 0, stream>>>(rse, csr, xc, b16B);
    spmm_bb<<<NB_SPMM, 256, 0, stream>>>(rse, csr, b16B, b16A);
    spmm_l3<<<(32768 * 16) / 256, 256, 0, stream>>>(
        rowlist, nrows, rse, csr, b16A, bufA);

    // ---- final dot ----
    dot_kernel<<<(BATCH * 64) / 256, 256, 0, stream>>>(
        user_indices, item_indices, bufA, out);
}

// Round 15
// 138.290 us; speedup vs baseline: 10.4609x; 1.0662x over previous
//
#include <hip/hip_runtime.h>

#define NUM_USERS 60000
#define NUM_ITEMS 40000
#define NUM_NODES 100000
#define DIM       64
#define NUM_EDGES 1200000
#define BATCH     16384

#define BROWS 256                 // rows per bucket
#define NBUCK 391                 // ceil(100000/256)
#define CAP   4096                // padded slots per bucket (mean 3072, +18 sigma)
#define EPB   4096                // edges per bin_edges block -> 293 blocks
#define BINBLK 512                // bin_edges block size
#define ZWORDS (512 + 256 + 3200) // gcursor + nrows + flags (contiguous)

// ---------------------------------------------------------------------------
// 0) convert fp32 embeddings -> concatenated bf16; block 0 zeroes counters
// ---------------------------------------------------------------------------
__device__ __forceinline__ unsigned short f2bf(float f) {
    unsigned u = __float_as_uint(f);
    unsigned r = (u + 0x7FFFu + ((u >> 16) & 1u)) >> 16;   // RNE
    return (unsigned short)r;
}

__global__ __launch_bounds__(256) void convert_emb(
    const float4* __restrict__ ue, const float4* __restrict__ ie,
    ushort4* __restrict__ xc, int* __restrict__ zbase)
{
    if (blockIdx.x == 0)
        for (int i = threadIdx.x; i < ZWORDS; i += 256) zbase[i] = 0;
    const int nU4 = NUM_USERS * (DIM / 4);       // 960000
    const int total4 = NUM_NODES * (DIM / 4);    // 1600000
    int i = blockIdx.x * blockDim.x + threadIdx.x;
    int stride = gridDim.x * blockDim.x;
    for (; i < total4; i += stride) {
        float4 v = (i < nU4) ? ue[i] : ie[i - nU4];
        ushort4 s;
        s.x = f2bf(v.x); s.y = f2bf(v.y); s.z = f2bf(v.z); s.w = f2bf(v.w);
        xc[i] = s;
    }
}

// ---------------------------------------------------------------------------
// 1) bin edges into 391 row-buckets (padded, cursors start at 0) + fused
//    batch-row flagging. Packed u64: [val:32][lrow:8][col:17]
// ---------------------------------------------------------------------------
__global__ __launch_bounds__(BINBLK) void bin_edges(
    const int* __restrict__ rows, const int* __restrict__ cols,
    const float* __restrict__ vals,
    const int* __restrict__ uidx, const int* __restrict__ iidx,
    int* __restrict__ gcursor, unsigned* __restrict__ flags,
    unsigned long long* __restrict__ tmp)
{
    __shared__ int cnt[NBUCK], lcur[NBUCK], gbase[NBUCK];
    int t = threadIdx.x;
    for (int i = t; i < NBUCK; i += BINBLK) { cnt[i] = 0; lcur[i] = 0; }
    // fused flag_batch: this block's slice of the 2*BATCH indices
    int fbase = blockIdx.x * 112;
    for (int k = t; k < 112; k += BINBLK) {
        int gi = fbase + k;
        if (gi < BATCH) {
            int n = uidx[gi];
            atomicOr(&flags[n >> 5], 1u << (n & 31));
        } else if (gi < 2 * BATCH) {
            int n = NUM_USERS + iidx[gi - BATCH];
            atomicOr(&flags[n >> 5], 1u << (n & 31));
        }
    }
    __syncthreads();
    int base = blockIdx.x * EPB;
    int lim = NUM_EDGES - base; if (lim > EPB) lim = EPB;
    for (int k = t; k < lim; k += BINBLK)
        atomicAdd(&cnt[rows[base + k] >> 8], 1);
    __syncthreads();
    for (int i = t; i < NBUCK; i += BINBLK) {
        int c = cnt[i];
        gbase[i] = c ? atomicAdd(&gcursor[i], c) : 0;
    }
    __syncthreads();
    for (int k = t; k < lim; k += BINBLK) {
        int idx = base + k;
        int r = rows[idx];
        int b = r >> 8;
        int lofs = atomicAdd(&lcur[b], 1);
        unsigned long long packed =
            ((unsigned long long)(unsigned)__float_as_int(vals[idx]) << 32)
            | ((unsigned)(r & 255) << 17) | (unsigned)cols[idx];
        tmp[(size_t)b * CAP + gbase[b] + lofs] = packed;
    }
}

// ---------------------------------------------------------------------------
// 2) per-bucket counting sort by lrow only (col order is null, round 10)
//    -> rse (start,end) + padded CSR at b*CAP. LDS ~35 KB -> 4 blocks/CU.
// ---------------------------------------------------------------------------
__global__ __launch_bounds__(256) void sort_buckets(
    const unsigned long long* __restrict__ tmp, const int* __restrict__ gcursor,
    int2* __restrict__ rse, int2* __restrict__ csr)
{
    __shared__ int lcnt[BROWS], rowcur[BROWS], sdata[BROWS];
    __shared__ int2 stage[CAP];   // 32 KB
    int b = blockIdx.x;
    int t = threadIdx.x;
    int count = gcursor[b];
    int base  = b * CAP;
    const unsigned long long* src = tmp + (size_t)base;
    lcnt[t] = 0;
    __syncthreads();
    for (int i = t; i < count; i += 256)
        atomicAdd(&lcnt[(int)((src[i] >> 17) & 255)], 1);
    __syncthreads();
    int myc = lcnt[t];
    sdata[t] = myc;
    __syncthreads();
    #pragma unroll
    for (int off = 1; off < 256; off <<= 1) {
        int x = (t >= off) ? sdata[t - off] : 0;
        __syncthreads();
        sdata[t] += x;
        __syncthreads();
    }
    int excl = sdata[t] - myc;
    rowcur[t] = excl;
    int row = b * BROWS + t;
    if (row < NUM_NODES)
        rse[row] = make_int2(base + excl, base + excl + myc);
    __syncthreads();
    for (int i = t; i < count; i += 256) {
        unsigned long long v = src[i];
        int lr = (int)((v >> 17) & 255);
        int pos = atomicAdd(&rowcur[lr], 1);
        stage[pos] = make_int2((int)(v & 0x1FFFF), (int)(v >> 32));
    }
    __syncthreads();
    for (int i = t; i < count; i += 256)
        csr[(size_t)base + i] = stage[i];
}

// ---------------------------------------------------------------------------
// needed-rows list for layer 3
// ---------------------------------------------------------------------------
__global__ __launch_bounds__(256) void compact_rows(
    const unsigned* __restrict__ flags, int* __restrict__ list,
    int* __restrict__ nrows)
{
    int i = blockIdx.x * blockDim.x + threadIdx.x;
    if (i < NUM_NODES && ((flags[i >> 5] >> (i & 31)) & 1u)) {
        int pos = atomicAdd(nrows, 1);
        list[pos] = i;
    }
}

// ---------------------------------------------------------------------------
// bf16 gather + row accumulate (16 lanes/row, ushort4 per lane, 4x unroll)
// ---------------------------------------------------------------------------
__device__ __forceinline__ float4 bf16_row(const unsigned short* x16, int c, int q)
{
    ushort4 h = *(const ushort4*)(x16 + ((size_t)c << 6) + (q << 2));
    float4 f;
    f.x = __uint_as_float((unsigned)h.x << 16);
    f.y = __uint_as_float((unsigned)h.y << 16);
    f.z = __uint_as_float((unsigned)h.z << 16);
    f.w = __uint_as_float((unsigned)h.w << 16);
    return f;
}

__device__ __forceinline__ float4 row_accum_bf16(
    int e, int end, int q, const int2* __restrict__ csr,
    const unsigned short* __restrict__ x16)
{
    float4 acc = make_float4(0.f, 0.f, 0.f, 0.f);
    for (; e + 3 < end; e += 4) {
        int2 p0 = csr[e], p1 = csr[e + 1], p2 = csr[e + 2], p3 = csr[e + 3];
        float4 x0 = bf16_row(x16, p0.x, q);
        float4 x1 = bf16_row(x16, p1.x, q);
        float4 x2 = bf16_row(x16, p2.x, q);
        float4 x3 = bf16_row(x16, p3.x, q);
        float v0 = __int_as_float(p0.y), v1 = __int_as_float(p1.y);
        float v2 = __int_as_float(p2.y), v3 = __int_as_float(p3.y);
        acc.x = fmaf(v0, x0.x, acc.x); acc.y = fmaf(v0, x0.y, acc.y);
        acc.z = fmaf(v0, x0.z, acc.z); acc.w = fmaf(v0, x0.w, acc.w);
        acc.x = fmaf(v1, x1.x, acc.x); acc.y = fmaf(v1, x1.y, acc.y);
        acc.z = fmaf(v1, x1.z, acc.z); acc.w = fmaf(v1, x1.w, acc.w);
        acc.x = fmaf(v2, x2.x, acc.x); acc.y = fmaf(v2, x2.y, acc.y);
        acc.z = fmaf(v2, x2.z, acc.z); acc.w = fmaf(v2, x2.w, acc.w);
        acc.x = fmaf(v3, x3.x, acc.x); acc.y = fmaf(v3, x3.y, acc.y);
        acc.z = fmaf(v3, x3.z, acc.z); acc.w = fmaf(v3, x3.w, acc.w);
    }
    for (; e < end; ++e) {
        int2 p0 = csr[e];
        float4 x0 = bf16_row(x16, p0.x, q);
        float v = __int_as_float(p0.y);
        acc.x = fmaf(v, x0.x, acc.x); acc.y = fmaf(v, x0.y, acc.y);
        acc.z = fmaf(v, x0.z, acc.z); acc.w = fmaf(v, x0.w, acc.w);
    }
    return acc;
}

// dense layer: bf16 in, bf16 out (layers 1 and 2)
__global__ __launch_bounds__(256) void spmm_bb(
    const int2* __restrict__ rse, const int2* __restrict__ csr,
    const unsigned short* __restrict__ x16, unsigned short* __restrict__ y16)
{
    int tid = blockIdx.x * blockDim.x + threadIdx.x;
    int row = tid >> 4;
    if (row >= NUM_NODES) return;
    int q = tid & 15;
    int2 se = rse[row];
    float4 a = row_accum_bf16(se.x, se.y, q, csr, x16);
    ushort4 s;
    s.x = f2bf(a.x); s.y = f2bf(a.y); s.z = f2bf(a.z); s.w = f2bf(a.w);
    *(ushort4*)(y16 + ((size_t)row << 6) + (q << 2)) = s;
}

// layer 3: listed rows only, bf16 in, fp32 out
__global__ __launch_bounds__(256) void spmm_l3(
    const int* __restrict__ list, const int* __restrict__ nrowsp,
    const int2* __restrict__ rse, const int2* __restrict__ csr,
    const unsigned short* __restrict__ x16, float* __restrict__ y)
{
    int tid = blockIdx.x * blockDim.x + threadIdx.x;
    int i = tid >> 4;
    if (i >= *nrowsp) return;
    int q = tid & 15;
    int row = list[i];
    int2 se = rse[row];
    float4 acc = row_accum_bf16(se.x, se.y, q, csr, x16);
    ((float4*)y)[((size_t)row << 4) + q] = acc;
}

// ---------------------------------------------------------------------------
// batched dot: one wave per batch element
// ---------------------------------------------------------------------------
__global__ __launch_bounds__(256) void dot_kernel(
    const int*   __restrict__ uidx,
    const int*   __restrict__ iidx,
    const float* __restrict__ x,
    float*       __restrict__ out)
{
    int wid  = (blockIdx.x * blockDim.x + threadIdx.x) >> 6;
    int lane = threadIdx.x & 63;
    if (wid >= BATCH) return;
    int u  = uidx[wid];
    int it = iidx[wid];
    float a = x[(size_t)u * DIM + lane];
    float bb = x[((size_t)NUM_USERS + it) * DIM + lane];
    float p = a * bb;
    #pragma unroll
    for (int off = 32; off > 0; off >>= 1)
        p += __shfl_down(p, off);
    if (lane == 0) out[wid] = p;
}

extern "C" void kernel_launch(void* const* d_in, const int* in_sizes, int n_in,
                              void* d_out, int out_size, void* d_ws, size_t ws_size,
                              hipStream_t stream)
{
    const int*   user_indices = (const int*)  d_in[0];
    const int*   item_indices = (const int*)  d_in[1];
    const int*   edge_rows    = (const int*)  d_in[2];
    const int*   edge_cols    = (const int*)  d_in[3];
    const float* edge_vals    = (const float*)d_in[4];
    const float* user_emb     = (const float*)d_in[5];
    const float* item_emb     = (const float*)d_in[6];
    float*       out          = (float*)      d_out;

    // ---- workspace layout ----
    // Alias: bufA (l3 fp32 out, 25.6 MB) overlays tmp (dead after sort_buckets)
    // + xc (dead after layer 1). l3 reads b16A (disjoint region).
    const size_t nfloats = (size_t)NUM_NODES * DIM;   // 6.4M elements
    char* p = (char*)d_ws;
    float* bufA = (float*)p;                            // 25.6 MB span (alias)
    unsigned long long* tmp = (unsigned long long*)p;
    p += (size_t)NBUCK * CAP * 8;                       // 12.81 MB
    unsigned short* xc   = (unsigned short*)p;  p += nfloats * 2;   // 12.8 MB
    unsigned short* b16B = (unsigned short*)p;  p += nfloats * 2;   // 12.8 MB
    unsigned short* b16A = (unsigned short*)p;  p += nfloats * 2;   // 12.8 MB
    int2*     rse     = (int2*)p;     p += 102400 * 8;
    // next three regions are contiguous; zeroed by convert_emb (ZWORDS words)
    int*      gcursor = (int*)p;      p += 512 * 4;
    int*      nrows   = (int*)p;      p += 256 * 4;
    unsigned* flags   = (unsigned*)p; p += 3200 * 4;
    int*      rowlist = (int*)p;      p += 33024 * 4;
    int2*     csr     = (int2*)p;     p += (size_t)NBUCK * CAP * 8; // 12.81 MB

    const int NB_BIN = (NUM_EDGES + EPB - 1) / EPB;   // 293

    // ---- convert (+ zero counters), bin (+flag), row sort, compact ----
    convert_emb<<<2048, 256, 0, stream>>>(
        (const float4*)user_emb, (const float4*)item_emb, (ushort4*)xc, gcursor);
    bin_edges<<<NB_BIN, BINBLK, 0, stream>>>(
        edge_rows, edge_cols, edge_vals, user_indices, item_indices,
        gcursor, flags, tmp);
    sort_buckets<<<NBUCK, 256, 0, stream>>>(tmp, gcursor, rse, csr);
    compact_rows<<<(NUM_NODES + 255) / 256, 256, 0, stream>>>(
        flags, rowlist, nrows);

    // ---- 3 SpMM layers: bf16->bf16, bf16->bf16, bf16->fp32(listed) ----
    const int NB_SPMM = (NUM_NODES * 16 + 255) / 256;   // 6250
    spmm_bb<<<NB_SPMM, 256, 0, stream>>>(rse, csr, xc, b16B);
    spmm_bb<<<NB_SPMM, 256, 0, stream>>>(rse, csr, b16B, b16A);
    spmm_l3<<<(32768 * 16) / 256, 256, 0, stream>>>(
        rowlist, nrows, rse, csr, b16A, bufA);

    // ---- final dot ----
    dot_kernel<<<(BATCH * 64) / 256, 256, 0, stream>>>(
        user_indices, item_indices, bufA, out);
}

// Round 16
// 126.097 us; speedup vs baseline: 11.4724x; 1.0967x over previous
//
#include <hip/hip_runtime.h>

#define NUM_USERS 60000
#define NUM_ITEMS 40000
#define NUM_NODES 100000
#define DIM       64
#define NUM_EDGES 1200000
#define BATCH     16384

#define BROWS 256                 // rows per bucket
#define NBUCK 391                 // ceil(100000/256)
#define CAP   4096                // padded slots per bucket (mean 3072, +18 sigma)
#define EPB   4096                // edges per bin block -> 293 bin blocks
#define PREPBLK 512               // prep kernel block size
#define NB_BIN 293                // (NUM_EDGES + EPB - 1) / EPB
#define NB_CONV 1024              // convert blocks inside prep
#define ZWORDS (512 + 256 + 3200) // gcursor + nrows + flags (contiguous)

// ---------------------------------------------------------------------------
// bf16 helpers
// ---------------------------------------------------------------------------
__device__ __forceinline__ unsigned short f2bf(float f) {
    unsigned u = __float_as_uint(f);
    unsigned r = (u + 0x7FFFu + ((u >> 16) & 1u)) >> 16;   // RNE
    return (unsigned short)r;
}
__device__ __forceinline__ unsigned pack2bf(float a, float b) {
    return (unsigned)f2bf(a) | ((unsigned)f2bf(b) << 16);
}

// ---------------------------------------------------------------------------
// 1) fused prep: blocks [0,NB_BIN) bin edges into 391 row-buckets (+ batch
//    flagging); blocks [NB_BIN, NB_BIN+NB_CONV) convert embeddings to bf16.
//    Both are independent memory-bound phases -> co-resident overlap.
//    Packed edge u64: [val:32][lrow:8][col:17]
// ---------------------------------------------------------------------------
__global__ __launch_bounds__(PREPBLK) void prep_kernel(
    const int* __restrict__ rows, const int* __restrict__ cols,
    const float* __restrict__ vals,
    const int* __restrict__ uidx, const int* __restrict__ iidx,
    const float4* __restrict__ ue, const float4* __restrict__ ie,
    ushort4* __restrict__ xc,
    int* __restrict__ gcursor, unsigned* __restrict__ flags,
    unsigned long long* __restrict__ tmp)
{
    __shared__ int cnt[NBUCK], lcur[NBUCK], gbase[NBUCK];
    int t = threadIdx.x;
    if (blockIdx.x >= NB_BIN) {
        // ---- convert branch ----
        const int nU4 = NUM_USERS * (DIM / 4);       // 960000
        const int total4 = NUM_NODES * (DIM / 4);    // 1600000
        int i = (blockIdx.x - NB_BIN) * PREPBLK + t;
        int stride = NB_CONV * PREPBLK;
        for (; i < total4; i += stride) {
            float4 v = (i < nU4) ? ue[i] : ie[i - nU4];
            ushort4 s;
            s.x = f2bf(v.x); s.y = f2bf(v.y); s.z = f2bf(v.z); s.w = f2bf(v.w);
            xc[i] = s;
        }
        return;
    }
    // ---- bin branch ----
    for (int i = t; i < NBUCK; i += PREPBLK) { cnt[i] = 0; lcur[i] = 0; }
    int fbase = blockIdx.x * 112;
    for (int k = t; k < 112; k += PREPBLK) {
        int gi = fbase + k;
        if (gi < BATCH) {
            int n = uidx[gi];
            atomicOr(&flags[n >> 5], 1u << (n & 31));
        } else if (gi < 2 * BATCH) {
            int n = NUM_USERS + iidx[gi - BATCH];
            atomicOr(&flags[n >> 5], 1u << (n & 31));
        }
    }
    __syncthreads();
    int base = blockIdx.x * EPB;
    int lim = NUM_EDGES - base; if (lim > EPB) lim = EPB;
    for (int k = t; k < lim; k += PREPBLK)
        atomicAdd(&cnt[rows[base + k] >> 8], 1);
    __syncthreads();
    for (int i = t; i < NBUCK; i += PREPBLK) {
        int c = cnt[i];
        gbase[i] = c ? atomicAdd(&gcursor[i], c) : 0;
    }
    __syncthreads();
    for (int k = t; k < lim; k += PREPBLK) {
        int idx = base + k;
        int r = rows[idx];
        int b = r >> 8;
        int lofs = atomicAdd(&lcur[b], 1);
        unsigned long long packed =
            ((unsigned long long)(unsigned)__float_as_int(vals[idx]) << 32)
            | ((unsigned)(r & 255) << 17) | (unsigned)cols[idx];
        tmp[(size_t)b * CAP + gbase[b] + lofs] = packed;
    }
}

// ---------------------------------------------------------------------------
// 2) per-bucket counting sort by lrow -> rse + padded CSR at b*CAP.
//    Fused: emit needed-rows list for layer 3 (flags -> rowlist/nrows).
// ---------------------------------------------------------------------------
__global__ __launch_bounds__(256) void sort_buckets(
    const unsigned long long* __restrict__ tmp, const int* __restrict__ gcursor,
    const unsigned* __restrict__ flags, int* __restrict__ rowlist,
    int* __restrict__ nrows,
    int2* __restrict__ rse, int2* __restrict__ csr)
{
    __shared__ int lcnt[BROWS], rowcur[BROWS], sdata[BROWS];
    __shared__ int2 stage[CAP];   // 32 KB
    int b = blockIdx.x;
    int t = threadIdx.x;
    int count = gcursor[b];
    int base  = b * CAP;
    const unsigned long long* src = tmp + (size_t)base;
    lcnt[t] = 0;
    __syncthreads();
    for (int i = t; i < count; i += 256)
        atomicAdd(&lcnt[(int)((src[i] >> 17) & 255)], 1);
    __syncthreads();
    int myc = lcnt[t];
    sdata[t] = myc;
    __syncthreads();
    #pragma unroll
    for (int off = 1; off < 256; off <<= 1) {
        int x = (t >= off) ? sdata[t - off] : 0;
        __syncthreads();
        sdata[t] += x;
        __syncthreads();
    }
    int excl = sdata[t] - myc;
    rowcur[t] = excl;
    int row = b * BROWS + t;
    if (row < NUM_NODES) {
        rse[row] = make_int2(base + excl, base + excl + myc);
        // fused compact_rows
        if ((flags[row >> 5] >> (row & 31)) & 1u) {
            int pos = atomicAdd(nrows, 1);
            rowlist[pos] = row;
        }
    }
    __syncthreads();
    for (int i = t; i < count; i += 256) {
        unsigned long long v = src[i];
        int lr = (int)((v >> 17) & 255);
        int pos = atomicAdd(&rowcur[lr], 1);
        stage[pos] = make_int2((int)(v & 0x1FFFF), (int)(v >> 32));
    }
    __syncthreads();
    for (int i = t; i < count; i += 256)
        csr[(size_t)base + i] = stage[i];
}

// ---------------------------------------------------------------------------
// bf16 gather + row accumulate: 8 lanes/row, uint4 (8 bf16) per lane,
// 4x unroll -> 32 independent 128B gathers in flight per wave.
// ---------------------------------------------------------------------------
__device__ __forceinline__ void fma8(
    float acc[8], unsigned long long hx, unsigned long long hy, float v)
{
    // hx = elems 0..3 (2 per u32), hy = elems 4..7
    unsigned h0 = (unsigned)hx, h1 = (unsigned)(hx >> 32);
    unsigned h2 = (unsigned)hy, h3 = (unsigned)(hy >> 32);
    acc[0] = fmaf(v, __uint_as_float(h0 << 16), acc[0]);
    acc[1] = fmaf(v, __uint_as_float(h0 & 0xFFFF0000u), acc[1]);
    acc[2] = fmaf(v, __uint_as_float(h1 << 16), acc[2]);
    acc[3] = fmaf(v, __uint_as_float(h1 & 0xFFFF0000u), acc[3]);
    acc[4] = fmaf(v, __uint_as_float(h2 << 16), acc[4]);
    acc[5] = fmaf(v, __uint_as_float(h2 & 0xFFFF0000u), acc[5]);
    acc[6] = fmaf(v, __uint_as_float(h3 << 16), acc[6]);
    acc[7] = fmaf(v, __uint_as_float(h3 & 0xFFFF0000u), acc[7]);
}

__device__ __forceinline__ void row_accum8(
    int e, int end, int q, const int2* __restrict__ csr,
    const unsigned short* __restrict__ x16, float acc[8])
{
    typedef unsigned long long u64;
    for (; e + 3 < end; e += 4) {
        int2 p0 = csr[e], p1 = csr[e + 1], p2 = csr[e + 2], p3 = csr[e + 3];
        const u64* s0 = (const u64*)(x16 + ((size_t)p0.x << 6) + (q << 3));
        const u64* s1 = (const u64*)(x16 + ((size_t)p1.x << 6) + (q << 3));
        const u64* s2 = (const u64*)(x16 + ((size_t)p2.x << 6) + (q << 3));
        const u64* s3 = (const u64*)(x16 + ((size_t)p3.x << 6) + (q << 3));
        u64 a0 = s0[0], b0 = s0[1];
        u64 a1 = s1[0], b1 = s1[1];
        u64 a2 = s2[0], b2 = s2[1];
        u64 a3 = s3[0], b3 = s3[1];
        fma8(acc, a0, b0, __int_as_float(p0.y));
        fma8(acc, a1, b1, __int_as_float(p1.y));
        fma8(acc, a2, b2, __int_as_float(p2.y));
        fma8(acc, a3, b3, __int_as_float(p3.y));
    }
    for (; e < end; ++e) {
        int2 p0 = csr[e];
        const u64* s0 = (const u64*)(x16 + ((size_t)p0.x << 6) + (q << 3));
        u64 a0 = s0[0], b0 = s0[1];
        fma8(acc, a0, b0, __int_as_float(p0.y));
    }
}

// dense layer: bf16 in, bf16 out (layers 1 and 2); 8 lanes/row
__global__ __launch_bounds__(256) void spmm_bb(
    const int2* __restrict__ rse, const int2* __restrict__ csr,
    const unsigned short* __restrict__ x16, unsigned short* __restrict__ y16)
{
    int tid = blockIdx.x * blockDim.x + threadIdx.x;
    int row = tid >> 3;
    if (row >= NUM_NODES) return;
    int q = tid & 7;
    int2 se = rse[row];
    float acc[8] = {0.f, 0.f, 0.f, 0.f, 0.f, 0.f, 0.f, 0.f};
    row_accum8(se.x, se.y, q, csr, x16, acc);
    uint4 s;
    s.x = pack2bf(acc[0], acc[1]);
    s.y = pack2bf(acc[2], acc[3]);
    s.z = pack2bf(acc[4], acc[5]);
    s.w = pack2bf(acc[6], acc[7]);
    *(uint4*)(y16 + ((size_t)row << 6) + (q << 3)) = s;
}

// layer 3: listed rows only, bf16 in, fp32 out; 8 lanes/row
__global__ __launch_bounds__(256) void spmm_l3(
    const int* __restrict__ list, const int* __restrict__ nrowsp,
    const int2* __restrict__ rse, const int2* __restrict__ csr,
    const unsigned short* __restrict__ x16, float* __restrict__ y)
{
    int tid = blockIdx.x * blockDim.x + threadIdx.x;
    int i = tid >> 3;
    if (i >= *nrowsp) return;
    int q = tid & 7;
    int row = list[i];
    int2 se = rse[row];
    float acc[8] = {0.f, 0.f, 0.f, 0.f, 0.f, 0.f, 0.f, 0.f};
    row_accum8(se.x, se.y, q, csr, x16, acc);
    float4* yb = (float4*)(y + ((size_t)row << 6) + (q << 3));
    yb[0] = make_float4(acc[0], acc[1], acc[2], acc[3]);
    yb[1] = make_float4(acc[4], acc[5], acc[6], acc[7]);
}

// ---------------------------------------------------------------------------
// batched dot: one wave per batch element
// ---------------------------------------------------------------------------
__global__ __launch_bounds__(256) void dot_kernel(
    const int*   __restrict__ uidx,
    const int*   __restrict__ iidx,
    const float* __restrict__ x,
    float*       __restrict__ out)
{
    int wid  = (blockIdx.x * blockDim.x + threadIdx.x) >> 6;
    int lane = threadIdx.x & 63;
    if (wid >= BATCH) return;
    int u  = uidx[wid];
    int it = iidx[wid];
    float a = x[(size_t)u * DIM + lane];
    float bb = x[((size_t)NUM_USERS + it) * DIM + lane];
    float p = a * bb;
    #pragma unroll
    for (int off = 32; off > 0; off >>= 1)
        p += __shfl_down(p, off);
    if (lane == 0) out[wid] = p;
}

extern "C" void kernel_launch(void* const* d_in, const int* in_sizes, int n_in,
                              void* d_out, int out_size, void* d_ws, size_t ws_size,
                              hipStream_t stream)
{
    const int*   user_indices = (const int*)  d_in[0];
    const int*   item_indices = (const int*)  d_in[1];
    const int*   edge_rows    = (const int*)  d_in[2];
    const int*   edge_cols    = (const int*)  d_in[3];
    const float* edge_vals    = (const float*)d_in[4];
    const float* user_emb     = (const float*)d_in[5];
    const float* item_emb     = (const float*)d_in[6];
    float*       out          = (float*)      d_out;

    // ---- workspace layout ----
    // Alias: bufA (l3 fp32 out, 25.6 MB) overlays tmp (dead after sort_buckets)
    // + xc (dead after layer 1). l3 reads b16A (disjoint region).
    const size_t nfloats = (size_t)NUM_NODES * DIM;   // 6.4M elements
    char* p = (char*)d_ws;
    float* bufA = (float*)p;                            // 25.6 MB span (alias)
    unsigned long long* tmp = (unsigned long long*)p;
    p += (size_t)NBUCK * CAP * 8;                       // 12.81 MB
    unsigned short* xc   = (unsigned short*)p;  p += nfloats * 2;   // 12.8 MB
    unsigned short* b16B = (unsigned short*)p;  p += nfloats * 2;   // 12.8 MB
    unsigned short* b16A = (unsigned short*)p;  p += nfloats * 2;   // 12.8 MB
    int2*     rse     = (int2*)p;     p += 102400 * 8;
    // next three regions contiguous; zeroed by the memset (ZWORDS words)
    int*      gcursor = (int*)p;      p += 512 * 4;
    int*      nrows   = (int*)p;      p += 256 * 4;
    unsigned* flags   = (unsigned*)p; p += 3200 * 4;
    int*      rowlist = (int*)p;      p += 33024 * 4;
    int2*     csr     = (int2*)p;     p += (size_t)NBUCK * CAP * 8; // 12.81 MB

    // ---- zero counters (15.9 KB), fused prep (bin || convert) ----
    hipMemsetAsync(gcursor, 0, ZWORDS * sizeof(int), stream);
    prep_kernel<<<NB_BIN + NB_CONV, PREPBLK, 0, stream>>>(
        edge_rows, edge_cols, edge_vals, user_indices, item_indices,
        (const float4*)user_emb, (const float4*)item_emb, (ushort4*)xc,
        gcursor, flags, tmp);
    sort_buckets<<<NBUCK, 256, 0, stream>>>(
        tmp, gcursor, flags, rowlist, nrows, rse, csr);

    // ---- 3 SpMM layers: bf16->bf16, bf16->bf16, bf16->fp32(listed) ----
    const int NB_SPMM = (NUM_NODES * 8 + 255) / 256;   // 3125
    spmm_bb<<<NB_SPMM, 256, 0, stream>>>(rse, csr, xc, b16B);
    spmm_bb<<<NB_SPMM, 256, 0, stream>>>(rse, csr, b16B, b16A);
    spmm_l3<<<(32768 * 8) / 256, 256, 0, stream>>>(
        rowlist, nrows, rse, csr, b16A, bufA);

    // ---- final dot ----
    dot_kernel<<<(BATCH * 64) / 256, 256, 0, stream>>>(
        user_indices, item_indices, bufA, out);
}